// Round 4
// baseline (867.192 us; speedup 1.0000x reference)
//
#include <hip/hip_runtime.h>
#include <stdint.h>

// CAN_Layer reduces exactly to: out[:, :2048] = out[:, 2048:] =
//   0.5 * (protein @ Wv_p + drug @ Wv_d)
// (seq-len 1 -> softmax over singleton axis == 1 -> attention = identity on V).
//
// Pipeline:
//   Pass 1a: cast+transpose Wv_p/Wv_d -> Wt bf16 [2048][4096] (B^T layout).
//   Pass 1b: cast protein|drug -> Abf bf16 [16384][4096].
//   Pass 2:  gemm8 — 256x256 tile, BK=64, 8 waves (2x4), software-pipelined
//            (ks, A-half) phase schedule: every phase drains LAST phase's
//            ds_reads (lgkmcnt(0)) and issues NEXT phase's reads before its
//            16-MFMA cluster -> LDS latency hides under MFMA. Row-XOR LDS
//            swizzle (0 conflicts, verified R2), global_load_lds(16B),
//            counted vmcnt (2/6, never 0 in loop), 4 barriers/tile,
//            chunked XCD swizzle (FETCH 197 MB ~ ideal, verified R3).
//
// R4 change vs R3 (373 us, MfmaUtil 31%): R3 read fragments in the same
// phase that consumed them -> LDS pipe time (~2300 cyc/CU/tile) serialized
// with MFMA (~2480). Now reads are one phase ahead into alternating register
// sets (aA/aB/bA/bB, in-place refill, register-neutral).

typedef __attribute__((ext_vector_type(8))) short short8;
typedef __attribute__((ext_vector_type(4))) float float4v;
typedef __attribute__((ext_vector_type(2))) unsigned int uint2v;

typedef const __attribute__((address_space(1))) unsigned int* gp_t;
typedef __attribute__((address_space(3))) unsigned int* lp_t;

#define M_DIM 16384
#define N_DIM 2048
#define K_DIM 4096
#define OUT_LD 4096

static __device__ __forceinline__ unsigned int pack_bf16x2(float x, float y) {
  union { float f; unsigned int u; } a, b;
  a.f = x; b.f = y;
  unsigned int ua = a.u + 0x8000u;
  unsigned int ub = b.u + 0x8000u;
  return __builtin_amdgcn_perm(ub, ua, 0x07060302u);
}

static __device__ __forceinline__ unsigned short f2bf(float x) {
  union { float f; unsigned int u; } a; a.f = x;
  return (unsigned short)((a.u + 0x8000u) >> 16);
}

// ---- Pass 1a: Wt[n][k] = bf16(W[k][n]), W = Wv_p (k<2048) else Wv_d ----
__global__ __launch_bounds__(256)
void prep_wt(const float* __restrict__ Wp, const float* __restrict__ Wd,
             unsigned short* __restrict__ Wt) {
  __shared__ float tile[32][33];
  const int k0 = blockIdx.x * 32;
  const int n0 = blockIdx.y * 32;
  const int tx = threadIdx.x;
  const int ty = threadIdx.y;
  const float* W = (k0 < 2048) ? Wp : Wd;
  const int kk0 = (k0 < 2048) ? k0 : k0 - 2048;
#pragma unroll
  for (int i = 0; i < 4; ++i) {
    int r = ty * 4 + i;
    tile[r][tx] = W[(size_t)(kk0 + r) * 2048 + n0 + tx];
  }
  __syncthreads();
#pragma unroll
  for (int i = 0; i < 4; ++i) {
    int r = ty * 4 + i;
    Wt[(size_t)(n0 + r) * (size_t)K_DIM + k0 + tx] = f2bf(tile[tx][r]);
  }
}

// ---- Pass 1b: Abf[m][k] = bf16([protein | drug][m][k]) ----
__global__ __launch_bounds__(256)
void cast_a(const float* __restrict__ P, const float* __restrict__ Dg,
            unsigned int* __restrict__ Abf) {
  int idx = blockIdx.x * 256 + threadIdx.x;
  int row = idx >> 10;
  int j = (idx & 1023) << 2;
  const float* src = (j < 2048) ? (P + (size_t)row * 2048 + j)
                                : (Dg + (size_t)row * 2048 + (j - 2048));
  float4v v = *(const float4v*)src;
  uint2v o;
  o.x = pack_bf16x2(v.x, v.y);
  o.y = pack_bf16x2(v.z, v.w);
  *(uint2v*)(Abf + (size_t)row * 2048 + (j >> 1)) = o;
}

// =====================================================================
// Pass 2 pipelined schedule (tile tt, buf b, nb=b^1). Phase = (ks, A-half):
//   P0: MFMA(aA=K0H0, bA=K0 -> acc[0..3])  reads aK0H1->aB;  stage tt+1 A1(nb)
//   P1: MFMA(aB=K0H1, bA=K0 -> acc[4..7])  reads bK1->bB, aK1H0->aA
//   P2: MFMA(aA=K1H0, bB=K1 -> acc[0..3])  reads aK1H1->aB;  VMW(2) entry
//   P3: MFMA(aB=K1H1, bB=K1 -> acc[4..7])  reads tt+1: aK0H0(nb)->aA,
//       bK0(nb)->bA; stage tt+2 A0,B0,B1(b); VMW(6) at end
// Every phase: BAR; [VMW]; lgkmcnt(0) [drains prev-phase reads]; stages;
// reads; sched_barrier(0); setprio(1); 16 MFMA; setprio(0).
// Ledger (verified): each region's stage issues >= 1 barrier after the
// covering lgkmcnt of its last reader; each cross-buffer read follows a
// counted VMW + barrier confirming its stages. lgkm outstanding <= 8.
// =====================================================================

#define VMW(N) asm volatile("s_waitcnt vmcnt(" #N ")" ::: "memory")
#define LGW0() asm volatile("s_waitcnt lgkmcnt(0)" ::: "memory")
#define BAR() __builtin_amdgcn_s_barrier()
#define SBAR0() __builtin_amdgcn_sched_barrier(0)
#define SP1 __builtin_amdgcn_s_setprio(1);
#define SP0 __builtin_amdgcn_s_setprio(0);

#define LOAD_A4(dst, base, H, KS)                                           \
  _Pragma("unroll") for (int i = 0; i < 4; ++i)                             \
    dst[i] = *(const short8*)&(base)[aoff + ((H)*4 + i) * 1024 +            \
                                     ((KS) ? c1 : c0)];

#define LOAD_B4(dst, base, KS)                                              \
  _Pragma("unroll") for (int j = 0; j < 4; ++j)                             \
    dst[j] = *(const short8*)&(base)[boff + j * 1024 + ((KS) ? c1 : c0)];

#define MFMA16(ASET, BSET, MB)                                              \
  _Pragma("unroll") for (int i = 0; i < 4; ++i)                             \
  _Pragma("unroll") for (int j = 0; j < 4; ++j)                             \
    acc[(MB) + i][j] = __builtin_amdgcn_mfma_f32_16x16x32_bf16(             \
        ASET[i], BSET[j], acc[(MB) + i][j], 0, 0, 0);

__global__ __launch_bounds__(512, 2)
void gemm8(const unsigned short* __restrict__ Abf,
           const unsigned short* __restrict__ Wt,
           float* __restrict__ out) {
  __shared__ unsigned short As[2][256 * 64];  // 64 KB
  __shared__ unsigned short Bs[2][256 * 64];  // 64 KB

  const int t = threadIdx.x;
  const int w = t >> 6, l = t & 63;
  const int wm = w >> 2, wn = w & 3;          // 2x4 wave grid
  const int lr = l & 15, q16 = l >> 4, xr = lr & 7;

  // Chunked XCD swizzle: XCD (bx&7) owns contiguous logical [x*64,(x+1)*64)
  const int bx = blockIdx.x;                  // 512 blocks
  const int logical = (bx & 7) * 64 + (bx >> 3);
  const int tn = logical & 7, tm = logical >> 3;
  const int m0 = tm << 8, n0 = tn << 8;

  // staging: row_in = t>>3, granule pos = t&7, swizzled src granule = pos^row
  const int srow = t >> 3;
  const int sk = (((t & 7) ^ (srow & 7)) << 3);
  const int brr = srow & 31;
  const int bsel = t >> 8;

  auto stage_a = [&](int buf, int k0, int h) {
#pragma unroll
    for (int sub = 0; sub < 2; ++sub) {
      const int row = m0 + sub * 128 + h * 64 + srow;
      const unsigned short* g = Abf + (size_t)row * K_DIM + (k0 + sk);
      const int ldsrow0 = sub * 128 + h * 64 + (w << 3);
      __builtin_amdgcn_global_load_lds((gp_t)(const void*)g,
                                       (lp_t)&As[buf][ldsrow0 * 64], 16, 0, 0);
    }
  };
  auto stage_b = [&](int buf, int k0, int nh) {
#pragma unroll
    for (int sub = 0; sub < 2; ++sub) {
      const int wnr = sub * 2 + bsel;
      const int ncol = n0 + wnr * 64 + nh * 32 + brr;
      const unsigned short* g = Wt + (size_t)ncol * K_DIM + (k0 + sk);
      const int ldsrow0 = wnr * 64 + nh * 32 + ((w & 3) << 3);
      __builtin_amdgcn_global_load_lds((gp_t)(const void*)g,
                                       (lp_t)&Bs[buf][ldsrow0 * 64], 16, 0, 0);
    }
  };

  float4v acc[8][4];
#pragma unroll
  for (int i = 0; i < 8; ++i)
#pragma unroll
    for (int j = 0; j < 4; ++j)
      acc[i][j] = (float4v){0.f, 0.f, 0.f, 0.f};

  const int aoff = (wm * 128 + lr) * 64;
  const int boff = (wn * 64 + lr) * 64;
  const int c0 = (q16 ^ xr) << 3;            // ks = 0 (swizzled granule)
  const int c1 = ((4 + q16) ^ xr) << 3;      // ks = 1

  short8 aA[4], aB[4], bA[4], bB[4];

  // ---- prologue: tile 0 fully + tile 1 {A0,B0,B1}; confirm tile 0;
  //      read tile 0's first-phase operands (drained at tt=0 P0's lgkm).
  stage_a(0, 0, 0);
  stage_a(0, 0, 1);
  stage_b(0, 0, 0);
  stage_b(0, 0, 1);
  stage_a(1, 64, 0);
  stage_b(1, 64, 0);
  stage_b(1, 64, 1);
  VMW(6);                 // 14 in flight -> retire tile 0's 8
  BAR();
  {
    unsigned short* Ac = &As[0][0];
    unsigned short* Bc = &Bs[0][0];
    LOAD_A4(aA, Ac, 0, 0)
    LOAD_B4(bA, Bc, 0)
  }

  // ---- main loop: tiles 0..61 (62,63 in epilogue) ----
  for (int tt = 0; tt < 62; ++tt) {
    const int buf = tt & 1;
    unsigned short* Ac = &As[buf][0];
    unsigned short* Bc = &Bs[buf][0];
    unsigned short* An = &As[buf ^ 1][0];
    unsigned short* Bn = &Bs[buf ^ 1][0];
    const int k1 = tt * 64 + 64;    // tile tt+1
    const int k2 = tt * 64 + 128;   // tile tt+2

    // P0: compute (K0,H0); read aK0H1; stage tt+1's A1 (region published now)
    BAR(); LGW0();
    stage_a(buf ^ 1, k1, 1);
    LOAD_A4(aB, Ac, 1, 0)
    SBAR0(); SP1 MFMA16(aA, bA, 0) SP0

    // P1: compute (K0,H1); read bK1, aK1H0
    BAR(); LGW0();
    LOAD_B4(bB, Bc, 1)
    LOAD_A4(aA, Ac, 0, 1)
    SBAR0(); SP1 MFMA16(aB, bA, 4) SP0

    // P2: compute (K1,H0); confirm tile tt+1 {A0,B0,B1}; read aK1H1
    BAR(); VMW(2); LGW0();
    LOAD_A4(aB, Ac, 1, 1)
    SBAR0(); SP1 MFMA16(aA, bB, 0) SP0

    // P3: compute (K1,H1); stage tt+2 {A0,B0,B1}; read tt+1's first operands
    BAR(); LGW0();
    stage_a(buf, k2, 0);
    stage_b(buf, k2, 0);
    stage_b(buf, k2, 1);
    LOAD_A4(aA, An, 0, 0)
    LOAD_B4(bA, Bn, 0)
    SBAR0(); SP1 MFMA16(aB, bB, 4) SP0
    VMW(6);               // retire tt+1's A1 (2) before tt+1 P0 reads it
  }

  // ---- epilogue: tiles 62 (buf0), 63 (buf1) ----
  {
    unsigned short* Ac0 = &As[0][0];
    unsigned short* Bc0 = &Bs[0][0];
    unsigned short* Ac1 = &As[1][0];
    unsigned short* Bc1 = &Bs[1][0];

    // tile 62
    BAR(); LGW0();
    stage_a(1, 4032, 1);            // tile 63's A1
    LOAD_A4(aB, Ac0, 1, 0)
    SBAR0(); SP1 MFMA16(aA, bA, 0) SP0
    BAR(); LGW0();
    LOAD_B4(bB, Bc0, 1)
    LOAD_A4(aA, Ac0, 0, 1)
    SBAR0(); SP1 MFMA16(aB, bA, 4) SP0
    BAR(); LGW0();
    LOAD_A4(aB, Ac0, 1, 1)
    SBAR0(); SP1 MFMA16(aA, bB, 0) SP0
    VMW(0);                         // tile 63 fully staged (8 -> 0)
    BAR(); LGW0();
    LOAD_A4(aA, Ac1, 0, 0)
    LOAD_B4(bA, Bc1, 0)
    SBAR0(); SP1 MFMA16(aB, bB, 4) SP0

    // tile 63
    LGW0();
    LOAD_A4(aB, Ac1, 1, 0)
    SBAR0(); SP1 MFMA16(aA, bA, 0) SP0
    LGW0();
    LOAD_B4(bB, Bc1, 1)
    LOAD_A4(aA, Ac1, 0, 1)
    SBAR0(); SP1 MFMA16(aB, bA, 4) SP0
    LGW0();
    LOAD_A4(aB, Ac1, 1, 1)
    SBAR0(); SP1 MFMA16(aA, bB, 0) SP0
    LGW0();
    SBAR0(); SP1 MFMA16(aB, bB, 4) SP0
  }

  // ---- C write: col = lane&15, row = (lane>>4)*4 + reg; both output halves
  const int rbase = m0 + wm * 128 + q16 * 4;
  const int cbase = n0 + wn * 64 + lr;
#pragma unroll
  for (int f = 0; f < 8; ++f)
#pragma unroll
    for (int j = 0; j < 4; ++j) {
      const int row = rbase + f * 16;
      const int col = cbase + j * 16;
#pragma unroll
      for (int r = 0; r < 4; ++r) {
        float v = acc[f][j][r] * 0.5f;
        size_t o = (size_t)(row + r) * (size_t)OUT_LD + col;
        out[o] = v;
        out[o + N_DIM] = v;
      }
    }
}

// ---- mid fallback (ws holds Wt only): fp32-A m97-style GEMM ----
__global__ __launch_bounds__(256)
void gemm_k(const float* __restrict__ Ap, const float* __restrict__ Ad,
            const unsigned short* __restrict__ Wt,
            float* __restrict__ out) {
  __shared__ unsigned short As[128 * 64];
  __shared__ unsigned short Bsm[128 * 64];

  const int t = threadIdx.x;
  const int bx = blockIdx.x;
  const int tn = bx & 15, tm = bx >> 4;
  const int m0 = tm << 7, n0 = tn << 7;
  const int w = t >> 6, l = t & 63;
  const int wmm = w & 1, wnn = w >> 1;
  const int lr = l & 15, q = l >> 4;

  const int rB = t >> 3;
  const int kB = (t & 7) * 8;

  float4v acc[4][4];
#pragma unroll
  for (int i = 0; i < 4; ++i)
#pragma unroll
    for (int j = 0; j < 4; ++j)
      acc[i][j] = (float4v){0.f, 0.f, 0.f, 0.f};

  for (int k0 = 0; k0 < K_DIM; k0 += 64) {
#pragma unroll
    for (int i = 0; i < 4; ++i) {
      const unsigned short* g =
          Wt + (size_t)(n0 + i * 32 + rB) * (size_t)K_DIM + (k0 + kB);
      __builtin_amdgcn_global_load_lds((gp_t)(const void*)g,
                                       (lp_t)&Bsm[i * 2048 + w * 512], 16, 0, 0);
    }
    {
      const float* base;
      int kk;
      if (k0 < 2048) { base = Ap; kk = k0; } else { base = Ad; kk = k0 - 2048; }
      const int rA = t >> 4;
      const int cA = (t & 15) * 4;
#pragma unroll
      for (int i = 0; i < 8; ++i) {
        int m = i * 16 + rA;
        float4v v = *(const float4v*)(base + (size_t)(m0 + m) * 2048 + kk + cA);
        uint2v o;
        o.x = pack_bf16x2(v.x, v.y);
        o.y = pack_bf16x2(v.z, v.w);
        *(uint2v*)&As[m * 64 + cA] = o;
      }
    }
    __syncthreads();

#pragma unroll
    for (int ks = 0; ks < 2; ++ks) {
      short8 a2[4], b2[4];
#pragma unroll
      for (int i = 0; i < 4; ++i) {
        a2[i] = *(const short8*)&As[(wmm * 64 + i * 16 + lr) * 64 + ks * 32 + q * 8];
        b2[i] = *(const short8*)&Bsm[(wnn * 64 + i * 16 + lr) * 64 + ks * 32 + q * 8];
      }
#pragma unroll
      for (int i = 0; i < 4; ++i)
#pragma unroll
        for (int j = 0; j < 4; ++j)
          acc[i][j] = __builtin_amdgcn_mfma_f32_16x16x32_bf16(a2[i], b2[j],
                                                              acc[i][j], 0, 0, 0);
    }
    __syncthreads();
  }

#pragma unroll
  for (int i = 0; i < 4; ++i) {
    const int r0 = m0 + wmm * 64 + i * 16 + q * 4;
#pragma unroll
    for (int j = 0; j < 4; ++j) {
      const int c = n0 + wnn * 64 + j * 16 + lr;
#pragma unroll
      for (int r = 0; r < 4; ++r) {
        float v = acc[i][j][r] * 0.5f;
        size_t o = (size_t)(r0 + r) * (size_t)OUT_LD + c;
        out[o] = v;
        out[o + 2048] = v;
      }
    }
  }
}

// ---- insurance fallback (no usable ws): fp32 LDS-tiled vector GEMM ----
__global__ __launch_bounds__(256)
void gemm_fallback(const float* __restrict__ P, const float* __restrict__ Dg,
                   const float* __restrict__ Wp, const float* __restrict__ Wd,
                   float* __restrict__ out) {
  __shared__ float Asf[64][17];
  __shared__ float Bsf[16][65];
  const int bx = blockIdx.x;
  const int by = blockIdx.y;
  const int t = threadIdx.x;
  const int tc = t & 15, trw = t >> 4;
  const int m0 = by * 64, n0 = bx * 64;
  float accf[4][4] = {};
  for (int k0 = 0; k0 < 4096; k0 += 16) {
    const float* Asrc = (k0 < 2048) ? P : Dg;
    const float* Bsrc = (k0 < 2048) ? Wp : Wd;
    const int kk = k0 & 2047;
#pragma unroll
    for (int i = 0; i < 4; ++i) {
      int r = i * 16 + trw;
      Asf[r][tc] = Asrc[(size_t)(m0 + r) * 2048 + kk + tc];
    }
#pragma unroll
    for (int i = 0; i < 4; ++i) {
      int r = i * 4 + (t >> 6);
      int c = t & 63;
      Bsf[r][c] = Bsrc[(size_t)(kk + r) * 2048 + n0 + c];
    }
    __syncthreads();
#pragma unroll
    for (int k2 = 0; k2 < 16; ++k2) {
      float a[4], b[4];
#pragma unroll
      for (int i = 0; i < 4; ++i) a[i] = Asf[trw * 4 + i][k2];
#pragma unroll
      for (int j = 0; j < 4; ++j) b[j] = Bsf[k2][tc * 4 + j];
#pragma unroll
      for (int i = 0; i < 4; ++i)
#pragma unroll
        for (int j = 0; j < 4; ++j) accf[i][j] += a[i] * b[j];
    }
    __syncthreads();
  }
#pragma unroll
  for (int i = 0; i < 4; ++i)
#pragma unroll
    for (int j = 0; j < 4; ++j) {
      float v = accf[i][j] * 0.5f;
      size_t o = (size_t)(m0 + trw * 4 + i) * 4096 + n0 + tc * 4 + j;
      out[o] = v;
      out[o + 2048] = v;
    }
}

extern "C" void kernel_launch(void* const* d_in, const int* in_sizes, int n_in,
                              void* d_out, int out_size, void* d_ws, size_t ws_size,
                              hipStream_t stream) {
  // setup_inputs order: protein, drug, mask_prot, mask_drug,
  //                     Wq_p, Wk_p, Wv_p, Wq_d, Wk_d, Wv_d
  const float* protein = (const float*)d_in[0];
  const float* drug    = (const float*)d_in[1];
  const float* Wv_p    = (const float*)d_in[6];
  const float* Wv_d    = (const float*)d_in[9];
  float* out = (float*)d_out;

  const size_t wt_bytes = (size_t)N_DIM * K_DIM * sizeof(unsigned short);  // 16.8 MB
  const size_t a_bytes  = (size_t)M_DIM * K_DIM * sizeof(unsigned short);  // 134 MB

  if (ws_size >= wt_bytes) {
    unsigned short* Wt = (unsigned short*)d_ws;
    prep_wt<<<dim3(128, 64), dim3(32, 8), 0, stream>>>(Wv_p, Wv_d, Wt);
    if (ws_size >= wt_bytes + a_bytes) {
      unsigned int* Abf = (unsigned int*)((char*)d_ws + wt_bytes);
      cast_a<<<65536, 256, 0, stream>>>(protein, drug, Abf);
      gemm8<<<512, 512, 0, stream>>>((const unsigned short*)Abf, Wt, out);
    } else {
      gemm_k<<<2048, 256, 0, stream>>>(protein, drug, Wt, out);
    }
  } else {
    gemm_fallback<<<dim3(32, 256), 256, 0, stream>>>(protein, drug, Wv_p, Wv_d, out);
  }
}

// Round 5
// 866.968 us; speedup vs baseline: 1.0003x; 1.0003x over previous
//
#include <hip/hip_runtime.h>
#include <stdint.h>

// CAN_Layer reduces exactly to: out[:, :2048] = out[:, 2048:] =
//   0.5 * (protein @ Wv_p + drug @ Wv_d)
// (seq-len 1 -> softmax over singleton axis == 1 -> attention = identity on V).
//
// Pipeline:
//   Pass 1a: cast+transpose Wv_p/Wv_d -> Wt bf16 [2048][4096] (B^T layout).
//   Pass 1b: cast protein|drug -> Abf bf16 [16384][4096].
//   Pass 2:  gemm8 — 256x256 tile, BK=64, 8 waves (2x4), one-barrier-per-phase
//            read-ahead pipeline: each phase MFMAs on registers read LAST
//            phase while issuing next phase's ds_reads; COMPILER interleaves
//            read-issue among MFMAs (no sched_barrier — R4's SBAR0 pinned
//            reads ahead of MFMAs and stalled the MFMA pipe at LDS-issue,
//            the documented m141 failure). LGW0 only before each publishing
//            barrier. Row-XOR LDS swizzle (0 conflicts, R2), counted vmcnt
//            (2/6, never 0 in loop), chunked XCD swizzle (FETCH~ideal, R3).

typedef __attribute__((ext_vector_type(8))) short short8;
typedef __attribute__((ext_vector_type(4))) float float4v;
typedef __attribute__((ext_vector_type(2))) unsigned int uint2v;

typedef const __attribute__((address_space(1))) unsigned int* gp_t;
typedef __attribute__((address_space(3))) unsigned int* lp_t;

#define M_DIM 16384
#define N_DIM 2048
#define K_DIM 4096
#define OUT_LD 4096

static __device__ __forceinline__ unsigned int pack_bf16x2(float x, float y) {
  union { float f; unsigned int u; } a, b;
  a.f = x; b.f = y;
  unsigned int ua = a.u + 0x8000u;
  unsigned int ub = b.u + 0x8000u;
  return __builtin_amdgcn_perm(ub, ua, 0x07060302u);
}

static __device__ __forceinline__ unsigned short f2bf(float x) {
  union { float f; unsigned int u; } a; a.f = x;
  return (unsigned short)((a.u + 0x8000u) >> 16);
}

// ---- Pass 1a: Wt[n][k] = bf16(W[k][n]), W = Wv_p (k<2048) else Wv_d ----
__global__ __launch_bounds__(256)
void prep_wt(const float* __restrict__ Wp, const float* __restrict__ Wd,
             unsigned short* __restrict__ Wt) {
  __shared__ float tile[32][33];
  const int k0 = blockIdx.x * 32;
  const int n0 = blockIdx.y * 32;
  const int tx = threadIdx.x;
  const int ty = threadIdx.y;
  const float* W = (k0 < 2048) ? Wp : Wd;
  const int kk0 = (k0 < 2048) ? k0 : k0 - 2048;
#pragma unroll
  for (int i = 0; i < 4; ++i) {
    int r = ty * 4 + i;
    tile[r][tx] = W[(size_t)(kk0 + r) * 2048 + n0 + tx];
  }
  __syncthreads();
#pragma unroll
  for (int i = 0; i < 4; ++i) {
    int r = ty * 4 + i;
    Wt[(size_t)(n0 + r) * (size_t)K_DIM + k0 + tx] = f2bf(tile[tx][r]);
  }
}

// ---- Pass 1b: Abf[m][k] = bf16([protein | drug][m][k]) ----
__global__ __launch_bounds__(256)
void cast_a(const float* __restrict__ P, const float* __restrict__ Dg,
            unsigned int* __restrict__ Abf) {
  int idx = blockIdx.x * 256 + threadIdx.x;
  int row = idx >> 10;
  int j = (idx & 1023) << 2;
  const float* src = (j < 2048) ? (P + (size_t)row * 2048 + j)
                                : (Dg + (size_t)row * 2048 + (j - 2048));
  float4v v = *(const float4v*)src;
  uint2v o;
  o.x = pack_bf16x2(v.x, v.y);
  o.y = pack_bf16x2(v.z, v.w);
  *(uint2v*)(Abf + (size_t)row * 2048 + (j >> 1)) = o;
}

// =====================================================================
// Pass 2 pipelined schedule (tile tt, buf b, nb=b^1). One BAR per phase.
// Zone p: [stages] [next-phase ds_reads] [16 MFMA on prev-phase regs,
// compiler-interleaved] [counted VMW where ledgered] LGW0 BAR.
//   A: MFMA(aA=K0H0, bA) -> acc[0..3]; read aB<-A1ks0; stage tt+1 A1(nb)
//   B: MFMA(aB=K0H1, bA) -> acc[4..7]; read bB<-Bks1, aA<-A0ks1
//   C: MFMA(aA=K1H0, bB) -> acc[0..3]; read aB<-A1ks1; VMW(2) [tt+1 A0B0B1]
//   D: MFMA(aB=K1H1, bB) -> acc[4..7]; stage tt+2 A0,B0,B1(b);
//      read aA<-nb A0ks0, bA<-nb Bks0; VMW(6) [tt+1 A1] after MFMA
// vmcnt ledger (verified): VMW(2)@C retires tt+1{A0,B0,B1}; VMW(6)@D
// retires tt+1{A1}; loop invariant 8 in flight. Region-overwrite: every
// stage issues >=1 barrier after the LGW0 covering its last reader.
// Tail: tile63 A1 staged in epilogue, covered by VMW(0)+BAR.
// =====================================================================

#define VMW(N) asm volatile("s_waitcnt vmcnt(" #N ")" ::: "memory")
#define LGW0() asm volatile("s_waitcnt lgkmcnt(0)" ::: "memory")
#define BAR() __builtin_amdgcn_s_barrier()
#define SP1 __builtin_amdgcn_s_setprio(1);
#define SP0 __builtin_amdgcn_s_setprio(0);

#define LOAD_A4(dst, base, H, KS)                                           \
  _Pragma("unroll") for (int i = 0; i < 4; ++i)                             \
    dst[i] = *(const short8*)&(base)[aoff + ((H)*4 + i) * 1024 +            \
                                     ((KS) ? c1 : c0)];

#define LOAD_B4(dst, base, KS)                                              \
  _Pragma("unroll") for (int j = 0; j < 4; ++j)                             \
    dst[j] = *(const short8*)&(base)[boff + j * 1024 + ((KS) ? c1 : c0)];

#define MFMA16(ASET, BSET, MB)                                              \
  _Pragma("unroll") for (int i = 0; i < 4; ++i)                             \
  _Pragma("unroll") for (int j = 0; j < 4; ++j)                             \
    acc[(MB) + i][j] = __builtin_amdgcn_mfma_f32_16x16x32_bf16(             \
        ASET[i], BSET[j], acc[(MB) + i][j], 0, 0, 0);

__global__ __launch_bounds__(512, 2)
void gemm8(const unsigned short* __restrict__ Abf,
           const unsigned short* __restrict__ Wt,
           float* __restrict__ out) {
  __shared__ unsigned short As[2][256 * 64];  // 64 KB
  __shared__ unsigned short Bs[2][256 * 64];  // 64 KB

  const int t = threadIdx.x;
  const int w = t >> 6, l = t & 63;
  const int wm = w >> 2, wn = w & 3;          // 2x4 wave grid
  const int lr = l & 15, q16 = l >> 4, xr = lr & 7;

  // Chunked XCD swizzle: XCD (bx&7) owns contiguous logical [x*64,(x+1)*64)
  const int bx = blockIdx.x;                  // 512 blocks
  const int logical = (bx & 7) * 64 + (bx >> 3);
  const int tn = logical & 7, tm = logical >> 3;
  const int m0 = tm << 8, n0 = tn << 8;

  // staging: row_in = t>>3, granule pos = t&7, swizzled src granule = pos^row
  const int srow = t >> 3;
  const int sk = (((t & 7) ^ (srow & 7)) << 3);
  const int brr = srow & 31;
  const int bsel = t >> 8;

  auto stage_a = [&](int buf, int k0, int h) {
#pragma unroll
    for (int sub = 0; sub < 2; ++sub) {
      const int row = m0 + sub * 128 + h * 64 + srow;
      const unsigned short* g = Abf + (size_t)row * K_DIM + (k0 + sk);
      const int ldsrow0 = sub * 128 + h * 64 + (w << 3);
      __builtin_amdgcn_global_load_lds((gp_t)(const void*)g,
                                       (lp_t)&As[buf][ldsrow0 * 64], 16, 0, 0);
    }
  };
  auto stage_b = [&](int buf, int k0, int nh) {
#pragma unroll
    for (int sub = 0; sub < 2; ++sub) {
      const int wnr = sub * 2 + bsel;
      const int ncol = n0 + wnr * 64 + nh * 32 + brr;
      const unsigned short* g = Wt + (size_t)ncol * K_DIM + (k0 + sk);
      const int ldsrow0 = wnr * 64 + nh * 32 + ((w & 3) << 3);
      __builtin_amdgcn_global_load_lds((gp_t)(const void*)g,
                                       (lp_t)&Bs[buf][ldsrow0 * 64], 16, 0, 0);
    }
  };

  float4v acc[8][4];
#pragma unroll
  for (int i = 0; i < 8; ++i)
#pragma unroll
    for (int j = 0; j < 4; ++j)
      acc[i][j] = (float4v){0.f, 0.f, 0.f, 0.f};

  const int aoff = (wm * 128 + lr) * 64;
  const int boff = (wn * 64 + lr) * 64;
  const int c0 = (q16 ^ xr) << 3;            // ks = 0 (swizzled granule)
  const int c1 = ((4 + q16) ^ xr) << 3;      // ks = 1

  short8 aA[4], aB[4], bA[4], bB[4];

  // ---- prologue: tile 0 fully + tile 1 {A0,B0,B1}; confirm tile 0;
  //      pre-read tile 0's first operands (compiler inserts the lgkm wait).
  stage_a(0, 0, 0);
  stage_a(0, 0, 1);
  stage_b(0, 0, 0);
  stage_b(0, 0, 1);
  stage_a(1, 64, 0);
  stage_b(1, 64, 0);
  stage_b(1, 64, 1);
  VMW(6);                 // 14 in flight -> retire tile 0's 8
  BAR();
  {
    unsigned short* Ac = &As[0][0];
    unsigned short* Bc = &Bs[0][0];
    LOAD_A4(aA, Ac, 0, 0)
    LOAD_B4(bA, Bc, 0)
  }

  // ---- main loop: tiles 0..61 (62,63 in epilogue) ----
  for (int tt = 0; tt < 62; ++tt) {
    const int buf = tt & 1;
    unsigned short* Ac = &As[buf][0];
    unsigned short* Bc = &Bs[buf][0];
    unsigned short* An = &As[buf ^ 1][0];
    unsigned short* Bn = &Bs[buf ^ 1][0];
    const int k1 = tt * 64 + 64;    // tile tt+1
    const int k2 = tt * 64 + 128;   // tile tt+2

    // Phase A: MFMA(K0,H0); read A1ks0; stage tt+1 A1 (region freed tt-1 C)
    stage_a(buf ^ 1, k1, 1);
    LOAD_A4(aB, Ac, 1, 0)
    SP1 MFMA16(aA, bA, 0) SP0
    LGW0(); BAR();

    // Phase B: MFMA(K0,H1); read Bks1, A0ks1
    LOAD_B4(bB, Bc, 1)
    LOAD_A4(aA, Ac, 0, 1)
    SP1 MFMA16(aB, bA, 4) SP0
    LGW0(); BAR();

    // Phase C: MFMA(K1,H0); confirm tt+1 {A0,B0,B1}; read A1ks1
    VMW(2);
    LOAD_A4(aB, Ac, 1, 1)
    SP1 MFMA16(aA, bB, 0) SP0
    LGW0(); BAR();

    // Phase D: MFMA(K1,H1); stage tt+2 {A0,B0,B1}; read tt+1 first operands;
    //          confirm tt+1 A1 after the MFMA cluster
    stage_a(buf, k2, 0);
    stage_b(buf, k2, 0);
    stage_b(buf, k2, 1);
    LOAD_A4(aA, An, 0, 0)
    LOAD_B4(bA, Bn, 0)
    SP1 MFMA16(aB, bB, 4) SP0
    VMW(6);
    LGW0(); BAR();
  }

  // ---- epilogue: tiles 62 (buf0), 63 (buf1) ----
  {
    unsigned short* Ac0 = &As[0][0];
    unsigned short* Bc0 = &Bs[0][0];
    unsigned short* Ac1 = &As[1][0];
    unsigned short* Bc1 = &Bs[1][0];

    // tile 63's A1 never had a stage slot (tt=62 Phase A doesn't run).
    // buf1 A1's last reader (tt=61 Phase C) drained/published -> safe.
    stage_a(1, 4032, 1);

    // tile 62 (operands aA,bA live from tt=61 Phase D)
    LOAD_A4(aB, Ac0, 1, 0)
    SP1 MFMA16(aA, bA, 0) SP0
    LGW0(); BAR();
    LOAD_B4(bB, Bc0, 1)
    LOAD_A4(aA, Ac0, 0, 1)
    SP1 MFMA16(aB, bA, 4) SP0
    LGW0(); BAR();
    LOAD_A4(aB, Ac0, 1, 1)
    SP1 MFMA16(aA, bB, 0) SP0
    LGW0(); BAR();
    VMW(0);                        // all of tile 63 landed (every wave's slice)
    BAR();
    LOAD_A4(aA, Ac1, 0, 0)
    LOAD_B4(bA, Bc1, 0)
    SP1 MFMA16(aB, bB, 4) SP0

    // tile 63: no further LDS writes -> no barriers; compiler orders waits
    LOAD_A4(aB, Ac1, 1, 0)
    SP1 MFMA16(aA, bA, 0) SP0
    LOAD_B4(bB, Bc1, 1)
    LOAD_A4(aA, Ac1, 0, 1)
    SP1 MFMA16(aB, bA, 4) SP0
    LOAD_A4(aB, Ac1, 1, 1)
    SP1 MFMA16(aA, bB, 0) SP0
    SP1 MFMA16(aB, bB, 4) SP0
  }

  // ---- C write: col = lane&15, row = (lane>>4)*4 + reg; both output halves
  const int rbase = m0 + wm * 128 + q16 * 4;
  const int cbase = n0 + wn * 64 + lr;
#pragma unroll
  for (int f = 0; f < 8; ++f)
#pragma unroll
    for (int j = 0; j < 4; ++j) {
      const int row = rbase + f * 16;
      const int col = cbase + j * 16;
#pragma unroll
      for (int r = 0; r < 4; ++r) {
        float v = acc[f][j][r] * 0.5f;
        size_t o = (size_t)(row + r) * (size_t)OUT_LD + col;
        out[o] = v;
        out[o + N_DIM] = v;
      }
    }
}

// ---- mid fallback (ws holds Wt only): fp32-A m97-style GEMM ----
__global__ __launch_bounds__(256)
void gemm_k(const float* __restrict__ Ap, const float* __restrict__ Ad,
            const unsigned short* __restrict__ Wt,
            float* __restrict__ out) {
  __shared__ unsigned short As[128 * 64];
  __shared__ unsigned short Bsm[128 * 64];

  const int t = threadIdx.x;
  const int bx = blockIdx.x;
  const int tn = bx & 15, tm = bx >> 4;
  const int m0 = tm << 7, n0 = tn << 7;
  const int w = t >> 6, l = t & 63;
  const int wmm = w & 1, wnn = w >> 1;
  const int lr = l & 15, q = l >> 4;

  const int rB = t >> 3;
  const int kB = (t & 7) * 8;

  float4v acc[4][4];
#pragma unroll
  for (int i = 0; i < 4; ++i)
#pragma unroll
    for (int j = 0; j < 4; ++j)
      acc[i][j] = (float4v){0.f, 0.f, 0.f, 0.f};

  for (int k0 = 0; k0 < K_DIM; k0 += 64) {
#pragma unroll
    for (int i = 0; i < 4; ++i) {
      const unsigned short* g =
          Wt + (size_t)(n0 + i * 32 + rB) * (size_t)K_DIM + (k0 + kB);
      __builtin_amdgcn_global_load_lds((gp_t)(const void*)g,
                                       (lp_t)&Bsm[i * 2048 + w * 512], 16, 0, 0);
    }
    {
      const float* base;
      int kk;
      if (k0 < 2048) { base = Ap; kk = k0; } else { base = Ad; kk = k0 - 2048; }
      const int rA = t >> 4;
      const int cA = (t & 15) * 4;
#pragma unroll
      for (int i = 0; i < 8; ++i) {
        int m = i * 16 + rA;
        float4v v = *(const float4v*)(base + (size_t)(m0 + m) * 2048 + kk + cA);
        uint2v o;
        o.x = pack_bf16x2(v.x, v.y);
        o.y = pack_bf16x2(v.z, v.w);
        *(uint2v*)&As[m * 64 + cA] = o;
      }
    }
    __syncthreads();

#pragma unroll
    for (int ks = 0; ks < 2; ++ks) {
      short8 a2[4], b2[4];
#pragma unroll
      for (int i = 0; i < 4; ++i) {
        a2[i] = *(const short8*)&As[(wmm * 64 + i * 16 + lr) * 64 + ks * 32 + q * 8];
        b2[i] = *(const short8*)&Bsm[(wnn * 64 + i * 16 + lr) * 64 + ks * 32 + q * 8];
      }
#pragma unroll
      for (int i = 0; i < 4; ++i)
#pragma unroll
        for (int j = 0; j < 4; ++j)
          acc[i][j] = __builtin_amdgcn_mfma_f32_16x16x32_bf16(a2[i], b2[j],
                                                              acc[i][j], 0, 0, 0);
    }
    __syncthreads();
  }

#pragma unroll
  for (int i = 0; i < 4; ++i) {
    const int r0 = m0 + wmm * 64 + i * 16 + q * 4;
#pragma unroll
    for (int j = 0; j < 4; ++j) {
      const int c = n0 + wnn * 64 + j * 16 + lr;
#pragma unroll
      for (int r = 0; r < 4; ++r) {
        float v = acc[i][j][r] * 0.5f;
        size_t o = (size_t)(r0 + r) * (size_t)OUT_LD + c;
        out[o] = v;
        out[o + 2048] = v;
      }
    }
  }
}

// ---- insurance fallback (no usable ws): fp32 LDS-tiled vector GEMM ----
__global__ __launch_bounds__(256)
void gemm_fallback(const float* __restrict__ P, const float* __restrict__ Dg,
                   const float* __restrict__ Wp, const float* __restrict__ Wd,
                   float* __restrict__ out) {
  __shared__ float Asf[64][17];
  __shared__ float Bsf[16][65];
  const int bx = blockIdx.x;
  const int by = blockIdx.y;
  const int t = threadIdx.x;
  const int tc = t & 15, trw = t >> 4;
  const int m0 = by * 64, n0 = bx * 64;
  float accf[4][4] = {};
  for (int k0 = 0; k0 < 4096; k0 += 16) {
    const float* Asrc = (k0 < 2048) ? P : Dg;
    const float* Bsrc = (k0 < 2048) ? Wp : Wd;
    const int kk = k0 & 2047;
#pragma unroll
    for (int i = 0; i < 4; ++i) {
      int r = i * 16 + trw;
      Asf[r][tc] = Asrc[(size_t)(m0 + r) * 2048 + kk + tc];
    }
#pragma unroll
    for (int i = 0; i < 4; ++i) {
      int r = i * 4 + (t >> 6);
      int c = t & 63;
      Bsf[r][c] = Bsrc[(size_t)(kk + r) * 2048 + n0 + c];
    }
    __syncthreads();
#pragma unroll
    for (int k2 = 0; k2 < 16; ++k2) {
      float a[4], b[4];
#pragma unroll
      for (int i = 0; i < 4; ++i) a[i] = Asf[trw * 4 + i][k2];
#pragma unroll
      for (int j = 0; j < 4; ++j) b[j] = Bsf[k2][tc * 4 + j];
#pragma unroll
      for (int i = 0; i < 4; ++i)
#pragma unroll
        for (int j = 0; j < 4; ++j) accf[i][j] += a[i] * b[j];
    }
    __syncthreads();
  }
#pragma unroll
  for (int i = 0; i < 4; ++i)
#pragma unroll
    for (int j = 0; j < 4; ++j) {
      float v = accf[i][j] * 0.5f;
      size_t o = (size_t)(m0 + trw * 4 + i) * 4096 + n0 + tc * 4 + j;
      out[o] = v;
      out[o + 2048] = v;
    }
}

extern "C" void kernel_launch(void* const* d_in, const int* in_sizes, int n_in,
                              void* d_out, int out_size, void* d_ws, size_t ws_size,
                              hipStream_t stream) {
  // setup_inputs order: protein, drug, mask_prot, mask_drug,
  //                     Wq_p, Wk_p, Wv_p, Wq_d, Wk_d, Wv_d
  const float* protein = (const float*)d_in[0];
  const float* drug    = (const float*)d_in[1];
  const float* Wv_p    = (const float*)d_in[6];
  const float* Wv_d    = (const float*)d_in[9];
  float* out = (float*)d_out;

  const size_t wt_bytes = (size_t)N_DIM * K_DIM * sizeof(unsigned short);  // 16.8 MB
  const size_t a_bytes  = (size_t)M_DIM * K_DIM * sizeof(unsigned short);  // 134 MB

  if (ws_size >= wt_bytes) {
    unsigned short* Wt = (unsigned short*)d_ws;
    prep_wt<<<dim3(128, 64), dim3(32, 8), 0, stream>>>(Wv_p, Wv_d, Wt);
    if (ws_size >= wt_bytes + a_bytes) {
      unsigned int* Abf = (unsigned int*)((char*)d_ws + wt_bytes);
      cast_a<<<65536, 256, 0, stream>>>(protein, drug, Abf);
      gemm8<<<512, 512, 0, stream>>>((const unsigned short*)Abf, Wt, out);
    } else {
      gemm_k<<<2048, 256, 0, stream>>>(protein, drug, Wt, out);
    }
  } else {
    gemm_fallback<<<dim3(32, 256), 256, 0, stream>>>(protein, drug, Wv_p, Wv_d, out);
  }
}